// Round 1
// 780.964 us; speedup vs baseline: 2.1052x; 2.1052x over previous
//
#include <hip/hip_runtime.h>

#define NN 2048
#define NE 32768
#define DF 2048
#define TOPK 20
#define RMAXF 1e-5f
#define MAXD 48          // supported max in-degree (Poisson(16), actual max well below)
#define MAXDQ (MAXD / 4) // 12 quad-levels of 4 packed edges
#define SENTW 0x08000800u // two packed sentinel ids (2048 -> PV[2048] == 0)

// ---------------- init: zero counters, sentinel-fill transposed in-edge table ----------------
__global__ __launch_bounds__(256) void init_kernel(int* __restrict__ outcnt, int* __restrict__ incur,
                                                   unsigned* __restrict__ T) {
    int i = blockIdx.x * 256 + threadIdx.x;
    if (i < MAXDQ * NN * 2) T[i] = SENTW;
    if (i < NN) { outcnt[i] = 0; incur[i] = 0; }
}

// ---------------- build: out-degree counts + transposed (CSC) quad-packed fill ----------------
// Level-major layout: quad-level q of node j lives at uint2 index q*NN + j.
// Slot p of node d: word = (p>>2)*(NN*2) + d*2 + ((p>>1)&1), halfword = p&1.
// Each slot is written by exactly one thread; And+Or only race with the *other* half of the
// same word (disjoint masks), so the pair is safe.
__global__ __launch_bounds__(256) void build_kernel(const int* __restrict__ ei, int* __restrict__ outcnt,
                                                    int* __restrict__ incur, unsigned* __restrict__ T) {
    int e = blockIdx.x * 256 + threadIdx.x;
    if (e >= NE) return;
    int s = ei[e];
    int d = ei[NE + e];
    atomicAdd(&outcnt[s], 1);
    int p = atomicAdd(&incur[d], 1);
    if (p < MAXD) {
        int wi = (p >> 2) * (NN * 2) + d * 2 + ((p >> 1) & 1);
        int sh = (p & 1) * 16;
        atomicAnd(&T[wi], ~(0xFFFFu << sh));
        atomicOr(&T[wi], ((unsigned)s) << sh);
    }
}

// ---------------- winv05 = 0.5/outdeg; per-64-node-group quad-level bound ----------------
__global__ __launch_bounds__(256) void meta_kernel(const int* __restrict__ outcnt, const int* __restrict__ incur,
                                                   float* __restrict__ winv05, int* __restrict__ gmaxq) {
    int tid = threadIdx.x;
#pragma unroll
    for (int l = 0; l < 8; ++l) {
        int j = tid + (l << 8);
        int c = outcnt[j];
        winv05[j] = c ? 0.5f / (float)c : 0.0f;  // deg==0 row spreads nothing
    }
    if (tid < 32) {
        int m = 0;
        for (int k = 0; k < 64; ++k) m = max(m, incur[tid * 64 + k]);
        m = min(m, MAXD);
        gmaxq[tid] = (m + 3) >> 2;
    }
}

// ---------------- per-source local push (gather form) + top-20 ----------------
// Strided ownership: thread t owns nodes {t + 256*l}. For a fixed l, a wave's 64 lanes own
// 64 consecutive nodes -> coalesced dwordx2 edge loads, wave-uniform level bound, and
// conflict-free strided LDS writes. R and P live in registers (owner-only access);
// PV (push value per out-edge = rn * 0.5/outdeg) is the only shared state.
__global__ __launch_bounds__(256, 8) void push_topk_kernel(const unsigned* __restrict__ Tw,
                                                           const float* __restrict__ winv05g,
                                                           const int* __restrict__ gmaxqg,
                                                           float* __restrict__ tkv, int* __restrict__ tki) {
    __shared__ float PV[NN + 4];  // PV[2048] is the always-zero sentinel slot
    __shared__ float cv[256];
    __shared__ int ci[256];
    __shared__ int sflag;
    __shared__ int swin;

    const int tid = threadIdx.x;
    const int row = blockIdx.x;
    const uint2* Tq = (const uint2*)Tw;

    float Rr[8], Pr[8], wv[8], dreg[8];
    int gmq[8];
#pragma unroll
    for (int l = 0; l < 8; ++l) {
        int j = tid + (l << 8);
        Rr[l] = 0.0f;
        Pr[l] = 0.0f;
        wv[l] = winv05g[j];
        gmq[l] = gmaxqg[j >> 6];
        PV[j] = 0.0f;
    }
    if (tid < 4) PV[NN + tid] = 0.0f;
    // fold reference round 1 (only the source is >= RMAX): P[row]=0.5, PV[row]=1.0*winv05[row]
    if ((row & 255) == tid) {
        int l = row >> 8;
        Pr[l] = 0.5f;
        PV[row] = wv[l];
    }
    __syncthreads();

    int flagreg = 1;
    while (flagreg) {
        // gather: d[j] = sum over in-edges (i->j) of PV[i]   (sentinel slots add PV[2048]=0)
#pragma unroll
        for (int l = 0; l < 8; ++l) {
            int j = tid + (l << 8);
            const uint2* colq = Tq + j;
            int gq = __builtin_amdgcn_readfirstlane(gmq[l]);  // wave-uniform bound
            float d = 0.0f;
            for (int q = 0; q < gq; ++q) {
                uint2 w = colq[q * NN];  // coalesced 512B/wave
                d += PV[w.x & 0xFFFFu];
                d += PV[w.x >> 16];
                d += PV[w.y & 0xFFFFu];
                d += PV[w.y >> 16];
            }
            dreg[l] = d;
        }
        __syncthreads();  // all PV reads done before PV is rewritten
        if (tid == 0) sflag = 0;
        __syncthreads();
        bool above = false;
#pragma unroll
        for (int l = 0; l < 8; ++l) {
            int j = tid + (l << 8);
            float rn = Rr[l] + dreg[l];
            if (rn >= RMAXF) {
                Pr[l] += 0.5f * rn;
                PV[j] = rn * wv[l];
                Rr[l] = 0.0f;
                above = true;
            } else {
                PV[j] = 0.0f;
                Rr[l] = rn;
            }
        }
        if (above) sflag = 1;  // racy 1-stores, benign
        __syncthreads();       // PV writes + sflag visible
        flagreg = sflag;
    }

    // top-20 of P (value desc, lowest index on ties -> matches stable lax.top_k)
    for (int s = 0; s < TOPK; ++s) {
        float bv = -2.0f;
        int bi = 0;
#pragma unroll
        for (int l = 0; l < 8; ++l) {
            float v = Pr[l];
            if (v > bv) { bv = v; bi = tid + (l << 8); }  // l ascending => index ascending; strict > keeps lowest
        }
        cv[tid] = bv;
        ci[tid] = bi;
        __syncthreads();
        for (int st = 128; st > 0; st >>= 1) {
            if (tid < st) {
                float ov = cv[tid + st];
                int oi = ci[tid + st];
                if (ov > cv[tid] || (ov == cv[tid] && oi < ci[tid])) { cv[tid] = ov; ci[tid] = oi; }
            }
            __syncthreads();
        }
        if (tid == 0) {
            tkv[row * TOPK + s] = cv[0];
            tki[row * TOPK + s] = ci[0];
            swin = ci[0];
        }
        __syncthreads();
        int wj = swin;
        if ((wj & 255) == tid) Pr[wj >> 8] = -1.0f;  // owner pops winner (P >= 0, safe sentinel)
    }
}

// ---------------- out[row] = sum_v w_v * feats[idx_v] ----------------
__global__ __launch_bounds__(256) void final_kernel(const float* __restrict__ feats, const float* __restrict__ tkv,
                                                    const int* __restrict__ tki, float* __restrict__ out) {
    __shared__ float wvs[TOPK];
    __shared__ int wis[TOPK];
    int row = blockIdx.x, tid = threadIdx.x;
    if (tid < TOPK) {
        wvs[tid] = tkv[row * TOPK + tid];
        wis[tid] = tki[row * TOPK + tid];
    }
    __syncthreads();
    int c0 = tid * 8;
    float4 a0 = {0, 0, 0, 0}, a1 = {0, 0, 0, 0};
    for (int v = 0; v < TOPK; ++v) {
        float w = wvs[v];
        int id = wis[v];
        const float4* fr = (const float4*)&feats[(size_t)id * DF + c0];
        float4 g0 = fr[0], g1 = fr[1];
        a0.x += w * g0.x; a0.y += w * g0.y; a0.z += w * g0.z; a0.w += w * g0.w;
        a1.x += w * g1.x; a1.y += w * g1.y; a1.z += w * g1.z; a1.w += w * g1.w;
    }
    float4* op = (float4*)&out[(size_t)row * DF + c0];
    op[0] = a0;
    op[1] = a1;
}

extern "C" void kernel_launch(void* const* d_in, const int* in_sizes, int n_in,
                              void* d_out, int out_size, void* d_ws, size_t ws_size,
                              hipStream_t stream) {
    const float* feats = (const float*)d_in[0];
    const int* ei = (const int*)d_in[1];
    float* out = (float*)d_out;

    int* outcnt = (int*)d_ws;                     // 2048
    int* incur = outcnt + NN;                     // 2048 (in-degree after build)
    float* winv05 = (float*)(incur + NN);         // 2048
    int* gmaxq = (int*)(winv05 + NN);             // 64 (32 used; keeps T 8B-aligned)
    unsigned* T = (unsigned*)(gmaxq + 64);        // 12*2048*2 = 49152 words (quad-packed CSC)
    float* tkv = (float*)(T + MAXDQ * NN * 2);    // 2048*20
    int* tki = (int*)(tkv + NN * TOPK);           // 2048*20

    init_kernel<<<(MAXDQ * NN * 2 + 255) / 256, 256, 0, stream>>>(outcnt, incur, T);
    build_kernel<<<(NE + 255) / 256, 256, 0, stream>>>(ei, outcnt, incur, T);
    meta_kernel<<<1, 256, 0, stream>>>(outcnt, incur, winv05, gmaxq);
    push_topk_kernel<<<NN, 256, 0, stream>>>(T, winv05, gmaxq, tkv, tki);
    final_kernel<<<NN, 256, 0, stream>>>(feats, tkv, tki, out);
}